// Round 7
// baseline (282.889 us; speedup 1.0000x reference)
//
#include <hip/hip_runtime.h>

typedef unsigned short u16;
typedef unsigned char u8;
typedef short s16x8 __attribute__((ext_vector_type(8)));
typedef unsigned short u16x4 __attribute__((ext_vector_type(4)));
typedef float f32x4 __attribute__((ext_vector_type(4)));
typedef int i32x4 __attribute__((ext_vector_type(4)));
typedef int i32x8 __attribute__((ext_vector_type(8)));

#define AS1 __attribute__((address_space(1)))
#define AS3 __attribute__((address_space(3)))

// async global->LDS, 16B per lane; LDS dest = wave-uniform base + lane*16
__device__ __forceinline__ void g2l16(const void* g, void* l) {
  __builtin_amdgcn_global_load_lds((const AS1 void*)g, (AS3 void*)l, 16, 0, 0);
}

__device__ __forceinline__ float b2f(u16 u) {
  union { unsigned int i; float f; } x; x.i = ((unsigned int)u) << 16; return x.f;
}
__device__ __forceinline__ u16 f2b(float f) {  // round-to-nearest-even
  unsigned int u = __builtin_bit_cast(unsigned int, f);
  return (u16)((u + 0x7fffu + ((u >> 16) & 1u)) >> 16);
}
__device__ __forceinline__ u8 f2e4m3(float v) {
  int p = __builtin_amdgcn_cvt_pk_fp8_f32(v, 0.f, 0, false);
  return (u8)(p & 0xff);
}
__device__ __forceinline__ float sigm(float x) { return 1.f / (1.f + __expf(-x)); }
__device__ __forceinline__ float tanh_f(float x) { return 2.f / (1.f + __expf(-2.f * x)) - 1.f; }

// dims: T=48 N=4096 F_IN=H1=F_OUT=64; TH = 3072

// ---------------- kprep: adj fp32->fp8 (x4096, coalesced) + weight prep ----------------
__global__ __launch_bounds__(256) void kprep(
    const float* __restrict__ a, u8* __restrict__ ab,
    const float* __restrict__ fcw,
    const float* __restrict__ Wz, const float* __restrict__ Wr, const float* __restrict__ Wh,
    const float* __restrict__ Lz, const float* __restrict__ Lr, const float* __restrict__ Lh,
    u16* __restrict__ fcwT, u16* __restrict__ wct, u16* __restrict__ lbt) {
  int b = blockIdx.x, t = threadIdx.x;
  if (b < 4096) {
    size_t idx = (size_t)b * 256 + t;   // lane-contiguous float4 index
    const float4* src = (const float4*)a;
    unsigned int* dst = (unsigned int*)ab;
#pragma unroll
    for (int k = 0; k < 4; ++k) {
      float4 v = src[idx + (size_t)k * 1048576];
      unsigned int p = __builtin_amdgcn_cvt_pk_fp8_f32(v.x * 4096.f, v.y * 4096.f, 0, false);
      p = __builtin_amdgcn_cvt_pk_fp8_f32(v.z * 4096.f, v.w * 4096.f, p, true);
      dst[idx + (size_t)k * 1048576] = p;
    }
    return;
  }
  int bb = b - 4096;
  if (bb < 48) {
    int idx = bb * 256 + t;          // 0..12287
    int c_cat = idx >> 6, hh = idx & 63;
    int g = c_cat >> 6, c = c_cat & 63;
    const float* W = (g == 0) ? Wz : (g == 1) ? Wr : Wh;
    const float* L = (g == 0) ? Lz : (g == 1) ? Lr : Lh;
    float acc = 0.f;
    for (int m = 0; m < 64; ++m) acc += W[hh * 64 + m] * L[m * 64 + c];
    wct[c_cat * 64 + hh] = f2b(acc);
  } else if (bb == 48) {
    for (int i = 0; i < 16; ++i) {
      int idx = t * 16 + i; int hh = idx >> 6, f = idx & 63;
      fcwT[hh * 64 + f] = f2b(fcw[f * 64 + hh]);
    }
  } else {
    int g = bb - 49;
    const float* L = (g == 0) ? Lz : (g == 1) ? Lr : Lh;
    for (int i = 0; i < 16; ++i) {
      int idx = t * 16 + i; int c = idx >> 6, hh = idx & 63;
      lbt[g * 4096 + c * 64 + hh] = f2b(L[(64 + hh) * 64 + c]);
    }
  }
}

// ---------------- k1: XHT[t*64+h][n] = relu(x[t]@fc_w + b)^T, fp8 out ----------------
// coalesced fp32 loads; result transposed through LDS [h][node]; 16B global stores
__global__ __launch_bounds__(256) void k1(
    const float* __restrict__ x, const float* __restrict__ fcb,
    const u16* __restrict__ fcwT, u8* __restrict__ xht) {
  __shared__ __align__(16) u16 xs[128 * 72];   // padded: 2-way banks
  __shared__ __align__(16) u16 fw[64 * 72];
  __shared__ __align__(16) u8 xh8[64 * 128];   // [h][node]
  __shared__ float fb[64];
  int tid = threadIdx.x, w = tid >> 6, l = tid & 63;
  int t = blockIdx.y, n0 = blockIdx.x * 128;
#pragma unroll
  for (int i2 = 0; i2 < 2; ++i2) {
    int g = tid + 256 * i2;
    s16x8 v = *(const s16x8*)&fcwT[g * 8];
    *(s16x8*)&fw[(g >> 3) * 72 + (g & 7) * 8] = v;
  }
  const float4* xg = (const float4*)(x + ((size_t)t * 4096 + n0) * 64);
#pragma unroll
  for (int i = 0; i < 8; ++i) {
    int f = tid + i * 256;             // lane-contiguous float4 index
    float4 v = xg[f];
    u16x4 p; p[0] = f2b(v.x); p[1] = f2b(v.y); p[2] = f2b(v.z); p[3] = f2b(v.w);
    *(u16x4*)&xs[(f >> 4) * 72 + (f & 15) * 4] = p;
  }
  if (tid < 64) fb[tid] = fcb[tid];
  __syncthreads();

  int lm = l & 15, q = l >> 4;
  f32x4 acc[4][2];
#pragma unroll
  for (int i = 0; i < 4; ++i)
#pragma unroll
    for (int j = 0; j < 2; ++j)
#pragma unroll
      for (int r = 0; r < 4; ++r) acc[i][j][r] = 0.f;
#pragma unroll
  for (int s = 0; s < 2; ++s) {
    s16x8 af[4], bf[2];
#pragma unroll
    for (int i = 0; i < 4; ++i) af[i] = *(const s16x8*)&fw[(16 * i + lm) * 72 + 32 * s + q * 8];
#pragma unroll
    for (int j = 0; j < 2; ++j) bf[j] = *(const s16x8*)&xs[(32 * w + 16 * j + lm) * 72 + 32 * s + q * 8];
#pragma unroll
    for (int i = 0; i < 4; ++i)
#pragma unroll
      for (int j = 0; j < 2; ++j)
        acc[i][j] = __builtin_amdgcn_mfma_f32_16x16x32_bf16(af[i], bf[j], acc[i][j], 0, 0, 0);
  }
#pragma unroll
  for (int i = 0; i < 4; ++i)
#pragma unroll
    for (int j = 0; j < 2; ++j) {
      int node = 32 * w + 16 * j + lm;
      int h0 = 16 * i + q * 4;
#pragma unroll
      for (int r = 0; r < 4; ++r) {
        float v = acc[i][j][r] + fb[h0 + r];
        xh8[(h0 + r) * 128 + node] = f2e4m3(v > 0.f ? v : 0.f);
      }
    }
  __syncthreads();
  {
    int h = tid >> 2, seg = tid & 3;   // 32 bytes per thread
    u8* dst = xht + (size_t)(t * 64 + h) * 4096 + n0 + seg * 32;
    const u8* src = &xh8[h * 128 + seg * 32];
    *(i32x4*)dst = *(const i32x4*)src;
    *(i32x4*)(dst + 16) = *(const i32x4*)(src + 16);
  }
}

// ---------------- k2: M = adj8 @ XH8, MX fp8 K=128 MFMA, rotation-swizzled LDS ----------------
// staging/fragment layout as round 5 (dense VMEM + conflict-free readback);
// epilogue transposes acc through reused staging LDS -> dwordx4 stores (full 64B/thread).
__global__ __launch_bounds__(256) void k2(
    const u8* __restrict__ A, const u8* __restrict__ B, u16* __restrict__ M) {
  __shared__ __align__(16) u8 sh[32768];
  u8* As = sh;
  u8* Bs = sh + 16384;
  int tid = threadIdx.x, w = tid >> 6, l = tid & 63;
  int nt = blockIdx.x, mt = blockIdx.y;
  const u8* Ab = A + (size_t)mt * 128 * 4096;
  const u8* Bb = B + (size_t)nt * 128 * 4096;
  int lm = l & 15, q = l >> 4;
  int wm = w >> 1, wn = w & 1;
  f32x4 acc[4][4];
#pragma unroll
  for (int i = 0; i < 4; ++i)
#pragma unroll
    for (int j = 0; j < 4; ++j)
#pragma unroll
      for (int r = 0; r < 4; ++r) acc[i][j][r] = 0.f;
  for (int k0b = 0; k0b < 4096; k0b += 128) {
#pragma unroll
    for (int j = 0; j < 4; ++j) {
      int r0 = 32 * w + 8 * j;
      int row = r0 + (l >> 3);
      int c = ((l & 7) - row) & 7;
      size_t go = (size_t)row * 4096 + k0b + c * 16;
      g2l16(Ab + go, (char*)As + r0 * 128);
      g2l16(Bb + go, (char*)Bs + r0 * 128);
    }
    __syncthreads();
    i32x8 a8[4], b8[4];
#pragma unroll
    for (int i = 0; i < 4; ++i) {
      int ra = 64 * wm + 16 * i + lm;
      int p0 = (2 * q + ra) & 7, p1 = (2 * q + 1 + ra) & 7;
      i32x4 lo = *(const i32x4*)&As[ra * 128 + p0 * 16];
      i32x4 hi = *(const i32x4*)&As[ra * 128 + p1 * 16];
      a8[i] = __builtin_shufflevector(lo, hi, 0, 1, 2, 3, 4, 5, 6, 7);
      int rb = 64 * wn + 16 * i + lm;
      int q0 = (2 * q + rb) & 7, q1 = (2 * q + 1 + rb) & 7;
      i32x4 lo2 = *(const i32x4*)&Bs[rb * 128 + q0 * 16];
      i32x4 hi2 = *(const i32x4*)&Bs[rb * 128 + q1 * 16];
      b8[i] = __builtin_shufflevector(lo2, hi2, 0, 1, 2, 3, 4, 5, 6, 7);
    }
#pragma unroll
    for (int i = 0; i < 4; ++i)
#pragma unroll
      for (int j = 0; j < 4; ++j)
        acc[i][j] = __builtin_amdgcn_mfma_scale_f32_16x16x128_f8f6f4(
            a8[i], b8[j], acc[i][j], 0, 0, 0, 127, 0, 127);  // fmt=fp8, scale=2^0
    __syncthreads();
  }
  // epilogue: 2-pass transpose through LDS. tb = [64][136] u16 (17.4KB)
  u16* tb = (u16*)sh;
  const float sc = 1.f / 4096.f;
#pragma unroll
  for (int p = 0; p < 2; ++p) {
    if (p) __syncthreads();            // pass-0 LDS reads done before overwrite
    if (wm == p) {
#pragma unroll
      for (int i = 0; i < 4; ++i)
#pragma unroll
        for (int j = 0; j < 4; ++j)
#pragma unroll
          for (int r = 0; r < 4; ++r)
            tb[(16 * i + 4 * q + r) * 136 + 64 * wn + 16 * j + lm] = f2b(acc[i][j][r] * sc);
    }
    __syncthreads();
    int row = tid >> 2, seg = tid & 3;   // 64 rows x 256B; 64B (32 u16) per thread
    u16* dst = M + (size_t)(mt * 128 + p * 64 + row) * 3072 + nt * 128 + seg * 32;
    const u16* src = &tb[row * 136 + seg * 32];
    *(i32x4*)dst = *(const i32x4*)src;
    *(i32x4*)(dst + 8)  = *(const i32x4*)(src + 8);
    *(i32x4*)(dst + 16) = *(const i32x4*)(src + 16);
    *(i32x4*)(dst + 24) = *(const i32x4*)(src + 24);
  }
}

// ---------------- k3: GRU scan; weights in regs, 2 barriers/step, h hi/lo in padded LDS ----------------
__global__ __launch_bounds__(256) void k3(
    const u16* __restrict__ M, const u16* __restrict__ wct, const u16* __restrict__ lbt,
    const float* __restrict__ bz, const float* __restrict__ br, const float* __restrict__ bh,
    float* __restrict__ out) {
  __shared__ __align__(16) u16 hhi[16 * 72], hlo[16 * 72];
  __shared__ __align__(16) u16 rhi[16 * 72], rlo[16 * 72];
  int tid = threadIdx.x, w = tid >> 6, l = tid & 63;
  int nb0 = blockIdx.x * 16;
  int lm = l & 15, q = l >> 4;
  int cb = 16 * w + q * 4;
  s16x8 afw[3][2], afl[3][2];
#pragma unroll
  for (int g = 0; g < 3; ++g)
#pragma unroll
    for (int s = 0; s < 2; ++s) {
      afw[g][s] = *(const s16x8*)&wct[(size_t)(g * 64 + 16 * w + lm) * 64 + 32 * s + q * 8];
      afl[g][s] = *(const s16x8*)&lbt[(size_t)(g * 64 + 16 * w + lm) * 64 + 32 * s + q * 8];
    }
  for (int i = tid; i < 16 * 72; i += 256) { hhi[i] = 0; hlo[i] = 0; }
  f32x4 bzv, brv, bhv, hv;
#pragma unroll
  for (int r = 0; r < 4; ++r) {
    bzv[r] = bz[cb + r]; brv[r] = br[cb + r]; bhv[r] = bh[cb + r]; hv[r] = 0.f;
  }
  __syncthreads();

  const u16* Mrow = M + (size_t)(nb0 + lm) * 3072;
  s16x8 Mn[2];
  Mn[0] = *(const s16x8*)&Mrow[q * 8];
  Mn[1] = *(const s16x8*)&Mrow[32 + q * 8];

  for (int t = 0; t < 48; ++t) {
    s16x8 Mc[2] = {Mn[0], Mn[1]};
    if (t < 47) {
      Mn[0] = *(const s16x8*)&Mrow[(t + 1) * 64 + q * 8];
      Mn[1] = *(const s16x8*)&Mrow[(t + 1) * 64 + 32 + q * 8];
    }
    f32x4 uz, ur;
#pragma unroll
    for (int r = 0; r < 4; ++r) { uz[r] = 0.f; ur[r] = 0.f; }
#pragma unroll
    for (int s = 0; s < 2; ++s) {
      s16x8 hh = *(const s16x8*)&hhi[lm * 72 + 32 * s + q * 8];
      s16x8 hl = *(const s16x8*)&hlo[lm * 72 + 32 * s + q * 8];
      uz = __builtin_amdgcn_mfma_f32_16x16x32_bf16(afw[0][s], Mc[s], uz, 0, 0, 0);
      uz = __builtin_amdgcn_mfma_f32_16x16x32_bf16(afl[0][s], hh, uz, 0, 0, 0);
      uz = __builtin_amdgcn_mfma_f32_16x16x32_bf16(afl[0][s], hl, uz, 0, 0, 0);
      ur = __builtin_amdgcn_mfma_f32_16x16x32_bf16(afw[1][s], Mc[s], ur, 0, 0, 0);
      ur = __builtin_amdgcn_mfma_f32_16x16x32_bf16(afl[1][s], hh, ur, 0, 0, 0);
      ur = __builtin_amdgcn_mfma_f32_16x16x32_bf16(afl[1][s], hl, ur, 0, 0, 0);
    }
    f32x4 zv, rv;
#pragma unroll
    for (int r = 0; r < 4; ++r) {
      zv[r] = sigm(uz[r] + bzv[r]);
      rv[r] = sigm(ur[r] + brv[r]);
    }
    {
      u16x4 phi, plo;
#pragma unroll
      for (int r = 0; r < 4; ++r) {
        float p = hv[r] * rv[r];
        u16 hi = f2b(p); phi[r] = hi; plo[r] = f2b(p - b2f(hi));
      }
      *(u16x4*)&rhi[lm * 72 + cb] = phi;
      *(u16x4*)&rlo[lm * 72 + cb] = plo;
    }
    __syncthreads();                   // h*r visible; all reads of h done
    f32x4 uh;
#pragma unroll
    for (int r = 0; r < 4; ++r) uh[r] = 0.f;
#pragma unroll
    for (int s = 0; s < 2; ++s) {
      s16x8 rh = *(const s16x8*)&rhi[lm * 72 + 32 * s + q * 8];
      s16x8 rl = *(const s16x8*)&rlo[lm * 72 + 32 * s + q * 8];
      uh = __builtin_amdgcn_mfma_f32_16x16x32_bf16(afw[2][s], Mc[s], uh, 0, 0, 0);
      uh = __builtin_amdgcn_mfma_f32_16x16x32_bf16(afl[2][s], rh, uh, 0, 0, 0);
      uh = __builtin_amdgcn_mfma_f32_16x16x32_bf16(afl[2][s], rl, uh, 0, 0, 0);
    }
    {
      u16x4 phi, plo;
#pragma unroll
      for (int r = 0; r < 4; ++r) {
        float th = tanh_f(uh[r] + bhv[r]);
        float hn = zv[r] * hv[r] + (1.f - zv[r]) * th;
        hv[r] = hn;
        u16 hi = f2b(hn); phi[r] = hi; plo[r] = f2b(hn - b2f(hi));
      }
      *(u16x4*)&hhi[lm * 72 + cb] = phi;
      *(u16x4*)&hlo[lm * 72 + cb] = plo;
    }
    __syncthreads();                   // h_{t+1} visible; r-buffer reads done
  }
#pragma unroll
  for (int r = 0; r < 4; ++r)
    out[(size_t)(nb0 + lm) * 64 + cb + r] = hv[r];
}

extern "C" void kernel_launch(void* const* d_in, const int* in_sizes, int n_in,
                              void* d_out, int out_size, void* d_ws, size_t ws_size,
                              hipStream_t stream) {
  const float* x   = (const float*)d_in[0];
  const float* adj = (const float*)d_in[1];
  const float* fcw = (const float*)d_in[2];
  const float* fcb = (const float*)d_in[3];
  const float* Wz  = (const float*)d_in[4];
  const float* Wr  = (const float*)d_in[5];
  const float* Wh  = (const float*)d_in[6];
  const float* Lz  = (const float*)d_in[7];
  const float* Lr  = (const float*)d_in[8];
  const float* Lh  = (const float*)d_in[9];
  const float* bz  = (const float*)d_in[10];
  const float* br  = (const float*)d_in[11];
  const float* bh  = (const float*)d_in[12];
  char* ws = (char*)d_ws;
  // ws layout (bytes):
  u8*  xht  = (u8*)(ws);                           // [3072][4096] fp8: 12,582,912
  u8*  adj8 = (u8*)(ws + (size_t)12582912);        // [4096][4096] fp8: 16,777,216
  u16* Mm   = (u16*)(ws + (size_t)29360128);       // [4096][3072] bf16: 25,165,824
  u16* fcwT = (u16*)(ws + (size_t)54525952);       // 8 KB
  u16* wct  = (u16*)(ws + (size_t)54534144);       // 24 KB
  u16* lbt  = (u16*)(ws + (size_t)54558720);       // 24 KB
  float* outp = (float*)d_out;

  hipLaunchKernelGGL(kprep, dim3(4148), dim3(256), 0, stream,
                     adj, adj8, fcw, Wz, Wr, Wh, Lz, Lr, Lh, fcwT, wct, lbt);
  hipLaunchKernelGGL(k1, dim3(32, 48), dim3(256), 0, stream, x, fcb, fcwT, xht);
  hipLaunchKernelGGL(k2, dim3(24, 32), dim3(256), 0, stream, adj8, xht, Mm);
  hipLaunchKernelGGL(k3, dim3(256), dim3(256), 0, stream, Mm, wct, lbt, bz, br, bh, outp);
}

// Round 8
// 261.103 us; speedup vs baseline: 1.0834x; 1.0834x over previous
//
#include <hip/hip_runtime.h>

typedef unsigned short u16;
typedef unsigned char u8;
typedef short s16x8 __attribute__((ext_vector_type(8)));
typedef unsigned short u16x4 __attribute__((ext_vector_type(4)));
typedef float f32x4 __attribute__((ext_vector_type(4)));
typedef int i32x4 __attribute__((ext_vector_type(4)));
typedef int i32x8 __attribute__((ext_vector_type(8)));

#define AS1 __attribute__((address_space(1)))
#define AS3 __attribute__((address_space(3)))

// async global->LDS, 16B per lane; LDS dest = wave-uniform base + lane*16
__device__ __forceinline__ void g2l16(const void* g, void* l) {
  __builtin_amdgcn_global_load_lds((const AS1 void*)g, (AS3 void*)l, 16, 0, 0);
}

__device__ __forceinline__ float b2f(u16 u) {
  union { unsigned int i; float f; } x; x.i = ((unsigned int)u) << 16; return x.f;
}
__device__ __forceinline__ u16 f2b(float f) {  // round-to-nearest-even
  unsigned int u = __builtin_bit_cast(unsigned int, f);
  return (u16)((u + 0x7fffu + ((u >> 16) & 1u)) >> 16);
}
__device__ __forceinline__ u8 f2e4m3(float v) {
  int p = __builtin_amdgcn_cvt_pk_fp8_f32(v, 0.f, 0, false);
  return (u8)(p & 0xff);
}
__device__ __forceinline__ float sigm(float x) { return 1.f / (1.f + __expf(-x)); }
__device__ __forceinline__ float tanh_f(float x) { return 2.f / (1.f + __expf(-2.f * x)) - 1.f; }

// dims: T=48 N=4096 F_IN=H1=F_OUT=64; TH = 3072

// ---------------- kpre: adj->fp8 + weight prep + k1 (XHT), one launch ----------------
// blocks [0,4096): adj fp32->fp8 e4m3 scaled x4096 (coalesced)
// blocks [4096,4144): wct;  [4144,4147): lbt;  [4147,5683): XHT tiles
__global__ __launch_bounds__(256) void kpre(
    const float* __restrict__ a, u8* __restrict__ ab,
    const float* __restrict__ fcw, const float* __restrict__ fcb,
    const float* __restrict__ x, u8* __restrict__ xht,
    const float* __restrict__ Wz, const float* __restrict__ Wr, const float* __restrict__ Wh,
    const float* __restrict__ Lz, const float* __restrict__ Lr, const float* __restrict__ Lh,
    u16* __restrict__ wct, u16* __restrict__ lbt) {
  int b = blockIdx.x, tid = threadIdx.x;
  if (b < 4096) {
    size_t idx = (size_t)b * 256 + tid;   // lane-contiguous float4 index
    const float4* src = (const float4*)a;
    unsigned int* dst = (unsigned int*)ab;
#pragma unroll
    for (int k = 0; k < 4; ++k) {
      float4 v = src[idx + (size_t)k * 1048576];
      unsigned int p = __builtin_amdgcn_cvt_pk_fp8_f32(v.x * 4096.f, v.y * 4096.f, 0, false);
      p = __builtin_amdgcn_cvt_pk_fp8_f32(v.z * 4096.f, v.w * 4096.f, p, true);
      dst[idx + (size_t)k * 1048576] = p;
    }
    return;
  }
  if (b < 4144) {
    int idx = (b - 4096) * 256 + tid;  // 0..12287
    int c_cat = idx >> 6, hh = idx & 63;
    int g = c_cat >> 6, c = c_cat & 63;
    const float* W = (g == 0) ? Wz : (g == 1) ? Wr : Wh;
    const float* L = (g == 0) ? Lz : (g == 1) ? Lr : Lh;
    float acc = 0.f;
    for (int m = 0; m < 64; ++m) acc += W[hh * 64 + m] * L[m * 64 + c];
    wct[c_cat * 64 + hh] = f2b(acc);
    return;
  }
  if (b < 4147) {
    int g = b - 4144;
    const float* L = (g == 0) ? Lz : (g == 1) ? Lr : Lh;
    for (int i = 0; i < 16; ++i) {
      int idx = tid * 16 + i; int c = idx >> 6, hh = idx & 63;
      lbt[g * 4096 + c * 64 + hh] = f2b(L[(64 + hh) * 64 + c]);
    }
    return;
  }
  // ---- XHT part: kb in [0,1536): t = kb>>5, n0 = (kb&31)*128 ----
  int kb = b - 4147;
  int t = kb >> 5, n0 = (kb & 31) * 128;
  __shared__ __align__(16) u16 xs[128 * 72];   // padded: 2-way banks
  __shared__ __align__(16) u16 fw[64 * 72];
  __shared__ __align__(16) u8 xh8[64 * 128];   // [h][node]
  __shared__ float fb[64];
  int w = tid >> 6, l = tid & 63;
#pragma unroll
  for (int i = 0; i < 16; ++i) {       // fw[h][f] = fc_w[f][h], coalesced fp32 reads
    int idx = tid + i * 256;
    int h = idx & 63, f = idx >> 6;
    fw[h * 72 + f] = f2b(fcw[f * 64 + h]);
  }
  const float4* xg = (const float4*)(x + ((size_t)t * 4096 + n0) * 64);
#pragma unroll
  for (int i = 0; i < 8; ++i) {
    int f = tid + i * 256;             // lane-contiguous float4 index
    float4 v = xg[f];
    u16x4 p; p[0] = f2b(v.x); p[1] = f2b(v.y); p[2] = f2b(v.z); p[3] = f2b(v.w);
    *(u16x4*)&xs[(f >> 4) * 72 + (f & 15) * 4] = p;
  }
  if (tid < 64) fb[tid] = fcb[tid];
  __syncthreads();

  int lm = l & 15, q = l >> 4;
  f32x4 acc[4][2];
#pragma unroll
  for (int i = 0; i < 4; ++i)
#pragma unroll
    for (int j = 0; j < 2; ++j)
#pragma unroll
      for (int r = 0; r < 4; ++r) acc[i][j][r] = 0.f;
#pragma unroll
  for (int s = 0; s < 2; ++s) {
    s16x8 af[4], bf[2];
#pragma unroll
    for (int i = 0; i < 4; ++i) af[i] = *(const s16x8*)&fw[(16 * i + lm) * 72 + 32 * s + q * 8];
#pragma unroll
    for (int j = 0; j < 2; ++j) bf[j] = *(const s16x8*)&xs[(32 * w + 16 * j + lm) * 72 + 32 * s + q * 8];
#pragma unroll
    for (int i = 0; i < 4; ++i)
#pragma unroll
      for (int j = 0; j < 2; ++j)
        acc[i][j] = __builtin_amdgcn_mfma_f32_16x16x32_bf16(af[i], bf[j], acc[i][j], 0, 0, 0);
  }
#pragma unroll
  for (int i = 0; i < 4; ++i)
#pragma unroll
    for (int j = 0; j < 2; ++j) {
      int node = 32 * w + 16 * j + lm;
      int h0 = 16 * i + q * 4;
#pragma unroll
      for (int r = 0; r < 4; ++r) {
        float v = acc[i][j][r] + fb[h0 + r];
        xh8[(h0 + r) * 128 + node] = f2e4m3(v > 0.f ? v : 0.f);
      }
    }
  __syncthreads();
  {
    int h = tid >> 2, seg = tid & 3;   // 32 bytes per thread
    u8* dst = xht + (size_t)(t * 64 + h) * 4096 + n0 + seg * 32;
    const u8* src = &xh8[h * 128 + seg * 32];
    *(i32x4*)dst = *(const i32x4*)src;
    *(i32x4*)(dst + 16) = *(const i32x4*)(src + 16);
  }
}

// ---------------- k2: M = adj8 @ XH8, MX fp8 K=128, 128x192 tile, rotation swizzle ----------------
__global__ __launch_bounds__(256) void k2(
    const u8* __restrict__ A, const u8* __restrict__ B, u16* __restrict__ M) {
  __shared__ __align__(16) u8 sh[40960];
  u8* As = sh;                    // 128 x 128B = 16KB
  u8* Bs = sh + 16384;            // 192 x 128B = 24KB
  int tid = threadIdx.x, w = tid >> 6, l = tid & 63;
  int nt = blockIdx.x, mt = blockIdx.y;
  const u8* Ab = A + (size_t)mt * 128 * 4096;
  const u8* Bb = B + (size_t)nt * 192 * 4096;
  int lm = l & 15, q = l >> 4;
  int wm = w >> 1, wn = w & 1;
  f32x4 acc[4][6];
#pragma unroll
  for (int i = 0; i < 4; ++i)
#pragma unroll
    for (int j = 0; j < 6; ++j)
#pragma unroll
      for (int r = 0; r < 4; ++r) acc[i][j][r] = 0.f;
  int srow = l >> 3;
  for (int k0b = 0; k0b < 4096; k0b += 128) {
#pragma unroll
    for (int j = 0; j < 4; ++j) {      // A: 32 rows/wave
      int r0 = 32 * w + 8 * j;
      int row = r0 + srow;
      int c = ((l & 7) - row) & 7;
      g2l16(Ab + (size_t)row * 4096 + k0b + c * 16, (char*)As + r0 * 128);
    }
#pragma unroll
    for (int j = 0; j < 6; ++j) {      // B: 48 rows/wave
      int r0 = 48 * w + 8 * j;
      int row = r0 + srow;
      int c = ((l & 7) - row) & 7;
      g2l16(Bb + (size_t)row * 4096 + k0b + c * 16, (char*)Bs + r0 * 128);
    }
    __syncthreads();
    i32x8 a8[4];
#pragma unroll
    for (int i = 0; i < 4; ++i) {
      int ra = 64 * wm + 16 * i + lm;
      int p0 = (2 * q + ra) & 7, p1 = (2 * q + 1 + ra) & 7;
      i32x4 lo = *(const i32x4*)&As[ra * 128 + p0 * 16];
      i32x4 hi = *(const i32x4*)&As[ra * 128 + p1 * 16];
      a8[i] = __builtin_shufflevector(lo, hi, 0, 1, 2, 3, 4, 5, 6, 7);
    }
#pragma unroll
    for (int j = 0; j < 6; ++j) {
      int rb = 96 * wn + 16 * j + lm;
      int q0 = (2 * q + rb) & 7, q1 = (2 * q + 1 + rb) & 7;
      i32x4 lo2 = *(const i32x4*)&Bs[rb * 128 + q0 * 16];
      i32x4 hi2 = *(const i32x4*)&Bs[rb * 128 + q1 * 16];
      i32x8 b8 = __builtin_shufflevector(lo2, hi2, 0, 1, 2, 3, 4, 5, 6, 7);
#pragma unroll
      for (int i = 0; i < 4; ++i)
        acc[i][j] = __builtin_amdgcn_mfma_scale_f32_16x16x128_f8f6f4(
            a8[i], b8, acc[i][j], 0, 0, 0, 127, 0, 127);  // fmt=fp8, scale=2^0
    }
    __syncthreads();
  }
  // epilogue: 2-pass transpose through LDS. tb = [64][200] u16 (25.6KB)
  u16* tb = (u16*)sh;
  const float sc = 1.f / 4096.f;
#pragma unroll
  for (int p = 0; p < 2; ++p) {
    if (p) __syncthreads();            // pass-0 LDS reads done before overwrite
    if (wm == p) {
#pragma unroll
      for (int i = 0; i < 4; ++i)
#pragma unroll
        for (int j = 0; j < 6; ++j)
#pragma unroll
          for (int r = 0; r < 4; ++r)
            tb[(16 * i + 4 * q + r) * 200 + 96 * wn + 16 * j + lm] = f2b(acc[i][j][r] * sc);
    }
    __syncthreads();
    int row = tid >> 2, seg = tid & 3;   // 64 rows x 384B; 96B (48 u16) per thread
    u16* dst = M + (size_t)(mt * 128 + p * 64 + row) * 3072 + nt * 192 + seg * 48;
    const u16* src = &tb[row * 200 + seg * 48];
#pragma unroll
    for (int v = 0; v < 6; ++v)
      *(i32x4*)(dst + 8 * v) = *(const i32x4*)(src + 8 * v);
  }
}

// ---------------- k3: GRU scan; weights in regs, 2 barriers/step, split acc chains ----------------
__global__ __launch_bounds__(256) void k3(
    const u16* __restrict__ M, const u16* __restrict__ wct, const u16* __restrict__ lbt,
    const float* __restrict__ bz, const float* __restrict__ br, const float* __restrict__ bh,
    float* __restrict__ out) {
  __shared__ __align__(16) u16 hhi[16 * 72], hlo[16 * 72];
  __shared__ __align__(16) u16 rhi[16 * 72], rlo[16 * 72];
  int tid = threadIdx.x, w = tid >> 6, l = tid & 63;
  int nb0 = blockIdx.x * 16;
  int lm = l & 15, q = l >> 4;
  int cb = 16 * w + q * 4;
  s16x8 afw[3][2], afl[3][2];
#pragma unroll
  for (int g = 0; g < 3; ++g)
#pragma unroll
    for (int s = 0; s < 2; ++s) {
      afw[g][s] = *(const s16x8*)&wct[(size_t)(g * 64 + 16 * w + lm) * 64 + 32 * s + q * 8];
      afl[g][s] = *(const s16x8*)&lbt[(size_t)(g * 64 + 16 * w + lm) * 64 + 32 * s + q * 8];
    }
  for (int i = tid; i < 16 * 72; i += 256) { hhi[i] = 0; hlo[i] = 0; }
  f32x4 bzv, brv, bhv, hv;
#pragma unroll
  for (int r = 0; r < 4; ++r) {
    bzv[r] = bz[cb + r]; brv[r] = br[cb + r]; bhv[r] = bh[cb + r]; hv[r] = 0.f;
  }
  __syncthreads();

  const u16* Mrow = M + (size_t)(nb0 + lm) * 3072;
  s16x8 Mn[2];
  Mn[0] = *(const s16x8*)&Mrow[q * 8];
  Mn[1] = *(const s16x8*)&Mrow[32 + q * 8];

  for (int t = 0; t < 48; ++t) {
    s16x8 Mc[2] = {Mn[0], Mn[1]};
    if (t < 47) {
      Mn[0] = *(const s16x8*)&Mrow[(t + 1) * 64 + q * 8];
      Mn[1] = *(const s16x8*)&Mrow[(t + 1) * 64 + 32 + q * 8];
    }
    f32x4 uzw, uzh, urw, urh;
#pragma unroll
    for (int r = 0; r < 4; ++r) { uzw[r] = 0.f; uzh[r] = 0.f; urw[r] = 0.f; urh[r] = 0.f; }
#pragma unroll
    for (int s = 0; s < 2; ++s) {
      s16x8 hh = *(const s16x8*)&hhi[lm * 72 + 32 * s + q * 8];
      s16x8 hl = *(const s16x8*)&hlo[lm * 72 + 32 * s + q * 8];
      uzw = __builtin_amdgcn_mfma_f32_16x16x32_bf16(afw[0][s], Mc[s], uzw, 0, 0, 0);
      uzh = __builtin_amdgcn_mfma_f32_16x16x32_bf16(afl[0][s], hh, uzh, 0, 0, 0);
      uzh = __builtin_amdgcn_mfma_f32_16x16x32_bf16(afl[0][s], hl, uzh, 0, 0, 0);
      urw = __builtin_amdgcn_mfma_f32_16x16x32_bf16(afw[1][s], Mc[s], urw, 0, 0, 0);
      urh = __builtin_amdgcn_mfma_f32_16x16x32_bf16(afl[1][s], hh, urh, 0, 0, 0);
      urh = __builtin_amdgcn_mfma_f32_16x16x32_bf16(afl[1][s], hl, urh, 0, 0, 0);
    }
    f32x4 zv, rv;
#pragma unroll
    for (int r = 0; r < 4; ++r) {
      zv[r] = sigm(uzw[r] + uzh[r] + bzv[r]);
      rv[r] = sigm(urw[r] + urh[r] + brv[r]);
    }
    {
      u16x4 phi, plo;
#pragma unroll
      for (int r = 0; r < 4; ++r) {
        float p = hv[r] * rv[r];
        u16 hi = f2b(p); phi[r] = hi; plo[r] = f2b(p - b2f(hi));
      }
      *(u16x4*)&rhi[lm * 72 + cb] = phi;
      *(u16x4*)&rlo[lm * 72 + cb] = plo;
    }
    __syncthreads();                   // h*r visible; all reads of h done
    f32x4 uhw, uhh;
#pragma unroll
    for (int r = 0; r < 4; ++r) { uhw[r] = 0.f; uhh[r] = 0.f; }
#pragma unroll
    for (int s = 0; s < 2; ++s) {
      s16x8 rh = *(const s16x8*)&rhi[lm * 72 + 32 * s + q * 8];
      s16x8 rl = *(const s16x8*)&rlo[lm * 72 + 32 * s + q * 8];
      uhw = __builtin_amdgcn_mfma_f32_16x16x32_bf16(afw[2][s], Mc[s], uhw, 0, 0, 0);
      uhh = __builtin_amdgcn_mfma_f32_16x16x32_bf16(afl[2][s], rh, uhh, 0, 0, 0);
      uhh = __builtin_amdgcn_mfma_f32_16x16x32_bf16(afl[2][s], rl, uhh, 0, 0, 0);
    }
    {
      u16x4 phi, plo;
#pragma unroll
      for (int r = 0; r < 4; ++r) {
        float th = tanh_f(uhw[r] + uhh[r] + bhv[r]);
        float hn = zv[r] * hv[r] + (1.f - zv[r]) * th;
        hv[r] = hn;
        u16 hi = f2b(hn); phi[r] = hi; plo[r] = f2b(hn - b2f(hi));
      }
      *(u16x4*)&hhi[lm * 72 + cb] = phi;
      *(u16x4*)&hlo[lm * 72 + cb] = plo;
    }
    __syncthreads();                   // h_{t+1} visible; r-buffer reads done
  }
#pragma unroll
  for (int r = 0; r < 4; ++r)
    out[(size_t)(nb0 + lm) * 64 + cb + r] = hv[r];
}

extern "C" void kernel_launch(void* const* d_in, const int* in_sizes, int n_in,
                              void* d_out, int out_size, void* d_ws, size_t ws_size,
                              hipStream_t stream) {
  const float* x   = (const float*)d_in[0];
  const float* adj = (const float*)d_in[1];
  const float* fcw = (const float*)d_in[2];
  const float* fcb = (const float*)d_in[3];
  const float* Wz  = (const float*)d_in[4];
  const float* Wr  = (const float*)d_in[5];
  const float* Wh  = (const float*)d_in[6];
  const float* Lz  = (const float*)d_in[7];
  const float* Lr  = (const float*)d_in[8];
  const float* Lh  = (const float*)d_in[9];
  const float* bz  = (const float*)d_in[10];
  const float* br  = (const float*)d_in[11];
  const float* bh  = (const float*)d_in[12];
  char* ws = (char*)d_ws;
  // ws layout (bytes):
  u8*  xht  = (u8*)(ws);                           // [3072][4096] fp8: 12,582,912
  u8*  adj8 = (u8*)(ws + (size_t)12582912);        // [4096][4096] fp8: 16,777,216
  u16* Mm   = (u16*)(ws + (size_t)29360128);       // [4096][3072] bf16: 25,165,824
  u16* wct  = (u16*)(ws + (size_t)54525952);       // 24 KB
  u16* lbt  = (u16*)(ws + (size_t)54550528);       // 24 KB
  float* outp = (float*)d_out;

  hipLaunchKernelGGL(kpre, dim3(5683), dim3(256), 0, stream,
                     adj, adj8, fcw, fcb, x, xht, Wz, Wr, Wh, Lz, Lr, Lh, wct, lbt);
  hipLaunchKernelGGL(k2, dim3(16, 32), dim3(256), 0, stream, adj8, xht, Mm);
  hipLaunchKernelGGL(k3, dim3(256), dim3(256), 0, stream, Mm, wct, lbt, bz, br, bh, outp);
}